// Round 9
// baseline (131.183 us; speedup 1.0000x reference)
//
#include <hip/hip_runtime.h>
#include <math.h>

typedef _Float16 half8 __attribute__((ext_vector_type(8)));
typedef _Float16 half4v __attribute__((ext_vector_type(4)));
typedef __fp16 fp16x2 __attribute__((ext_vector_type(2)));
typedef float floatx4 __attribute__((ext_vector_type(4)));

// ---------------------------------------------------------------------------
// Prep: hih = (f16)(E@W1a + b1), hjh = (f16)(E@W1b); W2/W3 pre-swizzled into
// MFMA fragment order. blocks 0..1023: one (b,s) row. block 1024: W2frag.
// block 1025: W3frag.
// ---------------------------------------------------------------------------
__global__ __launch_bounds__(256) void prep_kernel(
    const float* __restrict__ E,
    const float* __restrict__ W1,
    const float* __restrict__ b1,
    const float* __restrict__ W2,
    const float* __restrict__ W3,
    _Float16* __restrict__ hih,
    _Float16* __restrict__ hjh,
    _Float16* __restrict__ W2frag,
    _Float16* __restrict__ W3frag)
{
    const int blk = blockIdx.x;
    const int t = threadIdx.x;
    if (blk < 1024) {
        __shared__ float sE[128];
        if (t < 128) sE[t] = E[blk*128 + t];
        __syncthreads();
        const int half = t >> 7;       // 0: hi (with b1), 1: hj
        const int k = t & 127;
        float acc = half ? 0.f : b1[k];
        const float* w1col = &W1[half*128*128 + k];
        #pragma unroll 8
        for (int d = 0; d < 128; ++d)
            acc = fmaf(sE[d], w1col[d*128], acc);
        if (half == 0) hih[blk*128 + k] = (_Float16)acc;
        else           hjh[blk*128 + k] = (_Float16)acc;
    } else if (blk == 1024) {
        // A-frag order: frag g=(NT*4+ks), lane l, elem q holds
        // W2t[n][k]=W2[k][n], n=16*NT+(l&15), k=ks*32+(l>>4)*8+q
        for (int e = t; e < 16384; e += 256) {
            int q = e & 7, l = (e >> 3) & 63, g = e >> 9;
            int NT = g >> 2, ks = g & 3;
            int row = 16*NT + (l & 15);
            int k = ks*32 + (l >> 4)*8 + q;
            W2frag[e] = (_Float16)W2[k*128 + row];
        }
    } else {
        // B-frag order: frag ks, lane l, elem q holds W3[k][n2],
        // n2=l&15, k=ks*32+(l>>4)*8+q
        for (int e = t; e < 2048; e += 256) {
            int q = e & 7, l = (e >> 3) & 63, ks = e >> 9;
            int k = ks*32 + (l >> 4)*8 + q;
            W3frag[e] = (_Float16)W3[k*16 + (l & 15)];
        }
    }
}

// ---------------------------------------------------------------------------
// Main: one block = (b, i, j0..j0+127). BARRIER-FREE: each wave owns the
// 32-row m-strip [32*wave, 32*wave+32) of the LDS tile for ALL phases
// (hj staging, GEMM1' B-reads, H2 write-back, GEMM2 A-reads) — LDS is pure
// per-wave scratch, ordering enforced by the wave's own lgkmcnt waits.
// GEMM1' computes D[n][m] (n full 128, m = own strip); GEMM2 per strip.
// ---------------------------------------------------------------------------
__global__ __launch_bounds__(256, 3) void main_kernel(
    const _Float16* __restrict__ hih,
    const _Float16* __restrict__ hjh,
    const _Float16* __restrict__ W2frag,
    const _Float16* __restrict__ W3frag,
    const float* __restrict__ b2,
    const float* __restrict__ b3,
    const float* __restrict__ temps,
    const int* __restrict__ mask,
    float* __restrict__ out)
{
    constexpr int PADH = 136;            // f16 units; 272B row stride
    __shared__ _Float16 sH[128 * PADH];  // raw hj rows, then reused for H2

    const int tid = threadIdx.x;
    const int bid = blockIdx.x;
    const int b  = bid >> 11;
    const int i  = (bid >> 2) & 511;
    const int j0 = (bid & 3) << 7;

    const int lane = tid & 63;
    const int wave = tid >> 6;
    const int lr = lane & 15;
    const int lq = lane >> 4;
    const int m0 = 32*wave;              // this wave's m-strip

    const half8 zero8 = {};
    const _Float16* hirow = &hih[(b*512 + i)*128];
    const _Float16* hjbase = &hjh[(b*512 + j0)*128];
    const half8* w2v = (const half8*)W2frag;
    const half8* w3v = (const half8*)W3frag;

    // Early independent loads: hi fragments, mask (hide VMEM latency)
    half8 hiF[4];
    #pragma unroll
    for (int ks = 0; ks < 4; ++ks)
        hiF[ks] = *(const half8*)&hirow[ks*32 + lq*8];
    const int* mrow = &mask[(b*512 + i)*512];
    const int4 mk0 = *(const int4*)&mrow[j0 + m0 + 4*lq];
    const int4 mk1 = *(const int4*)&mrow[j0 + m0 + 16 + 4*lq];

    // Stage this wave's 32 raw hj rows (512 x 16B chunks, 8 per lane)
    #pragma unroll
    for (int kk = 0; kk < 8; ++kk) {
        const int c = kk*64 + lane;
        const int row = m0 + (c >> 4), col = c & 15;
        *(half8*)&sH[row*PADH + col*8] =
            *(const half8*)&hjbase[row*128 + col*8];
    }

    // GEMM1': D[n][m] = sum_k W2[k][n] * relu(hi[k]+hj[m][k]), m in own strip
    floatx4 acc[8][2] = {};
    #pragma unroll
    for (int ks = 0; ks < 4; ++ks) {
        const int kb = ks*32 + lq*8;
        half8 bF[2];
        #pragma unroll
        for (int mt = 0; mt < 2; ++mt) {
            const int m = m0 + 16*mt + lr;
            half8 hj8 = *(const half8*)&sH[m*PADH + kb];
            bF[mt] = __builtin_elementwise_max(hiF[ks] + hj8, zero8);
        }
        #pragma unroll
        for (int nt = 0; nt < 8; ++nt) {
            const half8 aW = w2v[(nt*4 + ks)*64 + lane];
            #pragma unroll
            for (int mt = 0; mt < 2; ++mt)
                acc[nt][mt] = __builtin_amdgcn_mfma_f32_16x16x32_f16(
                    aW, bF[mt], acc[nt][mt], 0, 0, 0);
        }
    }

    // H2[m][n] = relu(D + b2[n]) back into own strip rows (packed cvt)
    #pragma unroll
    for (int nt = 0; nt < 8; ++nt) {
        const int nb = 16*nt + 4*lq;
        const float4 bv = *(const float4*)&b2[nb];
        #pragma unroll
        for (int mt = 0; mt < 2; ++mt) {
            const int m = m0 + 16*mt + lr;
            floatx4 v = acc[nt][mt];
            fp16x2 lo = __builtin_amdgcn_cvt_pkrtz(
                fmaxf(v[0] + bv.x, 0.f), fmaxf(v[1] + bv.y, 0.f));
            fp16x2 hi = __builtin_amdgcn_cvt_pkrtz(
                fmaxf(v[2] + bv.z, 0.f), fmaxf(v[3] + bv.w, 0.f));
            half4v o;
            o[0] = (_Float16)lo[0]; o[1] = (_Float16)lo[1];
            o[2] = (_Float16)hi[0]; o[3] = (_Float16)hi[1];
            *(half4v*)&sH[m*PADH + nb] = o;
        }
    }

    // GEMM2: D2[m][n2] = sum_n H2[m][n] * W3[n][n2], own strip only
    floatx4 acc2[2] = {};
    #pragma unroll
    for (int ks = 0; ks < 4; ++ks) {
        const int k0 = ks*32 + lq*8;
        half8 bW = w3v[ks*64 + lane];
        half8 a0 = *(const half8*)&sH[(m0 + lr)*PADH + k0];
        half8 a1 = *(const half8*)&sH[(m0 + 16 + lr)*PADH + k0];
        acc2[0] = __builtin_amdgcn_mfma_f32_16x16x32_f16(a0, bW, acc2[0], 0, 0, 0);
        acc2[1] = __builtin_amdgcn_mfma_f32_16x16x32_f16(a1, bW, acc2[1], 0, 0, 0);
    }

    // Epilogue: bias = (comp + b3)*temp, mask -> -inf, float4 stores (f32 out)
    const int n2 = lr;
    const float tempv = temps[n2];
    const float b3v = b3[n2];
    float* outp = &out[(((b*16 + n2)*512) + i)*512];
    {
        const int j = j0 + m0 + 4*lq;
        floatx4 v = acc2[0];
        float4 res;
        res.x = mk0.x ? (v[0] + b3v)*tempv : -INFINITY;
        res.y = mk0.y ? (v[1] + b3v)*tempv : -INFINITY;
        res.z = mk0.z ? (v[2] + b3v)*tempv : -INFINITY;
        res.w = mk0.w ? (v[3] + b3v)*tempv : -INFINITY;
        *(float4*)&outp[j] = res;
    }
    {
        const int j = j0 + m0 + 16 + 4*lq;
        floatx4 v = acc2[1];
        float4 res;
        res.x = mk1.x ? (v[0] + b3v)*tempv : -INFINITY;
        res.y = mk1.y ? (v[1] + b3v)*tempv : -INFINITY;
        res.z = mk1.z ? (v[2] + b3v)*tempv : -INFINITY;
        res.w = mk1.w ? (v[3] + b3v)*tempv : -INFINITY;
        *(float4*)&outp[j] = res;
    }
}

extern "C" void kernel_launch(void* const* d_in, const int* in_sizes, int n_in,
                              void* d_out, int out_size, void* d_ws, size_t ws_size,
                              hipStream_t stream)
{
    const float* E     = (const float*)d_in[0];
    const int* mask    = (const int*)d_in[1];
    const float* W1    = (const float*)d_in[2];
    const float* b1    = (const float*)d_in[3];
    const float* W2    = (const float*)d_in[4];
    const float* b2    = (const float*)d_in[5];
    const float* W3    = (const float*)d_in[6];
    const float* b3    = (const float*)d_in[7];
    const float* temps = (const float*)d_in[8];

    char* ws = (char*)d_ws;
    _Float16* hih = (_Float16*)ws;                       // 1024*128 f16 = 256KB
    _Float16* hjh = (_Float16*)(ws + 262144);            // 256KB
    _Float16* W2f = (_Float16*)(ws + 524288);            // 32KB
    _Float16* W3f = W2f + 16384;                         // 4KB

    prep_kernel<<<1026, 256, 0, stream>>>(E, W1, b1, W2, W3, hih, hjh, W2f, W3f);
    main_kernel<<<4096, 256, 0, stream>>>(hih, hjh, W2f, W3f, b2, b3, temps, mask,
                                          (float*)d_out);
}

// Round 10
// 120.358 us; speedup vs baseline: 1.0899x; 1.0899x over previous
//
#include <hip/hip_runtime.h>
#include <math.h>

typedef _Float16 half8 __attribute__((ext_vector_type(8)));
typedef _Float16 half4v __attribute__((ext_vector_type(4)));
typedef float floatx4 __attribute__((ext_vector_type(4)));

// ---------------------------------------------------------------------------
// Prep: hih = (f16)(E@W1a + b1) linear; hjF = (f16)(E@W1b) PRE-SWIZZLED into
// MFMA B-fragment order per 16-row j-tile:
//   hjF[((jt*4+ks)*64 + lq*16+lr)*8 + q] = hj[16*jt+lr][ks*32+lq*8+q]
// so the main kernel's B-source is a coalesced per-lane half8, like W2frag.
// blocks 0..1023: one (b,s) row. block 1024: W2frag. block 1025: W3frag.
// ---------------------------------------------------------------------------
__global__ __launch_bounds__(256) void prep_kernel(
    const float* __restrict__ E,
    const float* __restrict__ W1,
    const float* __restrict__ b1,
    const float* __restrict__ W2,
    const float* __restrict__ W3,
    _Float16* __restrict__ hih,
    _Float16* __restrict__ hjF,
    _Float16* __restrict__ W2frag,
    _Float16* __restrict__ W3frag)
{
    const int blk = blockIdx.x;
    const int t = threadIdx.x;
    if (blk < 1024) {
        __shared__ float sE[128];
        if (t < 128) sE[t] = E[blk*128 + t];
        __syncthreads();
        const int half = t >> 7;       // 0: hi (with b1), 1: hj
        const int k = t & 127;
        float acc = half ? 0.f : b1[k];
        const float* w1col = &W1[half*128*128 + k];
        #pragma unroll 8
        for (int d = 0; d < 128; ++d)
            acc = fmaf(sE[d], w1col[d*128], acc);
        if (half == 0) {
            hih[blk*128 + k] = (_Float16)acc;
        } else {
            const int jt = blk >> 4, lr = blk & 15;
            const int ks = k >> 5, lq = (k >> 3) & 3, q = k & 7;
            hjF[(((jt*4 + ks)*64) + lq*16 + lr)*8 + q] = (_Float16)acc;
        }
    } else if (blk == 1024) {
        // A-frag order: frag g=((wr*4+nt)*4+ks), lane l, elem q holds
        // W2t[n][k]=W2[k][n], n=64*wr+16*nt+(l&15), k=ks*32+(l>>4)*8+q
        for (int e = t; e < 16384; e += 256) {
            int q = e & 7, l = (e >> 3) & 63, g = e >> 9;
            int wr = g >> 4, nt = (g >> 2) & 3, ks = g & 3;
            int row = 64*wr + 16*nt + (l & 15);
            int k = ks*32 + (l >> 4)*8 + q;
            W2frag[e] = (_Float16)W2[k*128 + row];
        }
    } else {
        // B-frag order: frag ks, lane l, elem q holds W3[k][n2],
        // n2=l&15, k=ks*32+(l>>4)*8+q
        for (int e = t; e < 2048; e += 256) {
            int q = e & 7, l = (e >> 3) & 63, ks = e >> 9;
            int k = ks*32 + (l >> 4)*8 + q;
            W3frag[e] = (_Float16)W3[k*16 + (l & 15)];
        }
    }
}

// ---------------------------------------------------------------------------
// Main: one block = (b, i, j0..j0+127). R7 register structure (aW[4][4]
// preloaded, wr/wc 2x2 wave split) but hj comes straight from pre-swizzled
// global hjF (coalesced 16B/lane) — NO LDS staging for hj. LDS holds only
// the H2 C->A round-trip; exactly ONE barrier.
// ---------------------------------------------------------------------------
__global__ __launch_bounds__(256, 3) void main_kernel(
    const _Float16* __restrict__ hih,
    const _Float16* __restrict__ hjF,
    const _Float16* __restrict__ W2frag,
    const _Float16* __restrict__ W3frag,
    const float* __restrict__ b2,
    const float* __restrict__ b3,
    const float* __restrict__ temps,
    const int* __restrict__ mask,
    float* __restrict__ out)
{
    constexpr int PADH = 136;            // f16 units; 272B row stride
    __shared__ _Float16 sH[128 * PADH];  // H2 only

    const int tid = threadIdx.x;
    const int bid = blockIdx.x;
    const int b  = bid >> 11;
    const int i  = (bid >> 2) & 511;
    const int j0 = (bid & 3) << 7;

    const int lane = tid & 63;
    const int wave = tid >> 6;
    const int wr = wave >> 1;   // n-strip (64)
    const int wc = wave & 1;    // m-strip (64)
    const int lr = lane & 15;
    const int lq = lane >> 4;

    const half8 zero8 = {};
    const _Float16* hirow = &hih[(b*512 + i)*128];
    const half8* w2v = (const half8*)W2frag;
    const half8* w3v = (const half8*)W3frag;
    const half8* hjv = (const half8*)hjF;
    // j-tile base for this block (+ wc strip): tiles of 16 j-rows
    const int jt0 = b*32 + (bid & 3)*8 + wc*4;

    // Preload W2 A-fragments (as R7: hoisted, 72-VGPR regime)
    half8 aW[4][4];
    #pragma unroll
    for (int nt = 0; nt < 4; ++nt)
        #pragma unroll
        for (int ks = 0; ks < 4; ++ks)
            aW[nt][ks] = w2v[((wr*4 + nt)*4 + ks)*64 + lane];

    // hi fragments + mask (early, independent)
    half8 hiF[4];
    #pragma unroll
    for (int ks = 0; ks < 4; ++ks)
        hiF[ks] = *(const half8*)&hirow[ks*32 + lq*8];
    const int* mrow = &mask[(b*512 + i)*512];
    const int m0e = 32*wave;             // epilogue/GEMM2 strip
    const int4 mk0 = *(const int4*)&mrow[j0 + m0e + 4*lq];
    const int4 mk1 = *(const int4*)&mrow[j0 + m0e + 16 + 4*lq];

    // GEMM1': D[n][m] = sum_k W2[k][n] * relu(hi[k]+hj[m][k])
    floatx4 acc[4][4] = {};
    #pragma unroll
    for (int ks = 0; ks < 4; ++ks) {
        half8 bF[4];
        #pragma unroll
        for (int mt = 0; mt < 4; ++mt) {
            half8 hj8 = hjv[((jt0 + mt)*4 + ks)*64 + lane];
            bF[mt] = __builtin_elementwise_max(hiF[ks] + hj8, zero8);
        }
        #pragma unroll
        for (int nt = 0; nt < 4; ++nt)
            #pragma unroll
            for (int mt = 0; mt < 4; ++mt)
                acc[nt][mt] = __builtin_amdgcn_mfma_f32_16x16x32_f16(
                    aW[nt][ks], bF[mt], acc[nt][mt], 0, 0, 0);
    }

    // H2[m][n] = relu(D + b2[n]); rows m in wc-strip, cols nb in wr-strip
    #pragma unroll
    for (int nt = 0; nt < 4; ++nt) {
        const int nb = 64*wr + 16*nt + 4*lq;
        const float4 bv = *(const float4*)&b2[nb];
        #pragma unroll
        for (int mt = 0; mt < 4; ++mt) {
            const int m = 64*wc + 16*mt + lr;
            floatx4 v = acc[nt][mt];
            half4v o;
            o[0] = (_Float16)fmaxf(v[0] + bv.x, 0.f);
            o[1] = (_Float16)fmaxf(v[1] + bv.y, 0.f);
            o[2] = (_Float16)fmaxf(v[2] + bv.z, 0.f);
            o[3] = (_Float16)fmaxf(v[3] + bv.w, 0.f);
            *(half4v*)&sH[m*PADH + nb] = o;
        }
    }
    __syncthreads();   // the only barrier (cols split across wr-waves)

    // GEMM2: D2[m][n2] = sum_n H2[m][n] * W3[n][n2], 32-row strip per wave
    floatx4 acc2[2] = {};
    #pragma unroll
    for (int ks = 0; ks < 4; ++ks) {
        const int k0 = ks*32 + lq*8;
        half8 bW = w3v[ks*64 + lane];
        half8 a0 = *(const half8*)&sH[(m0e + lr)*PADH + k0];
        half8 a1 = *(const half8*)&sH[(m0e + 16 + lr)*PADH + k0];
        acc2[0] = __builtin_amdgcn_mfma_f32_16x16x32_f16(a0, bW, acc2[0], 0, 0, 0);
        acc2[1] = __builtin_amdgcn_mfma_f32_16x16x32_f16(a1, bW, acc2[1], 0, 0, 0);
    }

    // Epilogue: bias = (comp + b3)*temp, mask -> -inf, float4 stores (f32 out)
    const int n2 = lr;
    const float tempv = temps[n2];
    const float b3v = b3[n2];
    float* outp = &out[(((b*16 + n2)*512) + i)*512];
    {
        const int j = j0 + m0e + 4*lq;
        floatx4 v = acc2[0];
        float4 res;
        res.x = mk0.x ? (v[0] + b3v)*tempv : -INFINITY;
        res.y = mk0.y ? (v[1] + b3v)*tempv : -INFINITY;
        res.z = mk0.z ? (v[2] + b3v)*tempv : -INFINITY;
        res.w = mk0.w ? (v[3] + b3v)*tempv : -INFINITY;
        *(float4*)&outp[j] = res;
    }
    {
        const int j = j0 + m0e + 16 + 4*lq;
        floatx4 v = acc2[1];
        float4 res;
        res.x = mk1.x ? (v[0] + b3v)*tempv : -INFINITY;
        res.y = mk1.y ? (v[1] + b3v)*tempv : -INFINITY;
        res.z = mk1.z ? (v[2] + b3v)*tempv : -INFINITY;
        res.w = mk1.w ? (v[3] + b3v)*tempv : -INFINITY;
        *(float4*)&outp[j] = res;
    }
}

extern "C" void kernel_launch(void* const* d_in, const int* in_sizes, int n_in,
                              void* d_out, int out_size, void* d_ws, size_t ws_size,
                              hipStream_t stream)
{
    const float* E     = (const float*)d_in[0];
    const int* mask    = (const int*)d_in[1];
    const float* W1    = (const float*)d_in[2];
    const float* b1    = (const float*)d_in[3];
    const float* W2    = (const float*)d_in[4];
    const float* b2    = (const float*)d_in[5];
    const float* W3    = (const float*)d_in[6];
    const float* b3    = (const float*)d_in[7];
    const float* temps = (const float*)d_in[8];

    char* ws = (char*)d_ws;
    _Float16* hih = (_Float16*)ws;                       // 1024*128 f16 = 256KB
    _Float16* hjF = (_Float16*)(ws + 262144);            // 256KB (swizzled)
    _Float16* W2f = (_Float16*)(ws + 524288);            // 32KB
    _Float16* W3f = W2f + 16384;                         // 4KB

    prep_kernel<<<1026, 256, 0, stream>>>(E, W1, b1, W2, W3, hih, hjF, W2f, W3f);
    main_kernel<<<4096, 256, 0, stream>>>(hih, hjF, W2f, W3f, b2, b3, temps, mask,
                                          (float*)d_out);
}